// Round 1
// baseline (188.810 us; speedup 1.0000x reference)
//
#include <hip/hip_runtime.h>
#include <hip/hip_bf16.h>

#define HH 512
#define WW 512
#define NJ 250
#define NBINS 8192

// ---------------- Kernel A: histogram of valid heatmap values ----------------
__global__ void hist_kernel(const float* __restrict__ hm,
                            unsigned* __restrict__ cnt,
                            float* __restrict__ sm,
                            unsigned* __restrict__ vc) {
    int idx = blockIdx.x * blockDim.x + threadIdx.x;
    int stride = gridDim.x * blockDim.x;
    unsigned local_valid = 0;
    for (int i = idx; i < HH * WW; i += stride) {
        float v = hm[i];
        if (v > 0.001f) {
            local_valid++;
            int b = (int)(v * (float)NBINS);
            b = min(max(b, 0), NBINS - 1);
            atomicAdd(&cnt[b], 1u);
            atomicAdd(&sm[b], v);
        }
    }
    atomicAdd(vc, local_valid);
}

// ---------------- Kernel B: find top-k sum -> max20 ----------------
// 256 threads, 32 bins per thread, bins walked in DESCENDING value order.
__global__ void select_kernel(const unsigned* __restrict__ cnt,
                              const float* __restrict__ sm,
                              const unsigned* __restrict__ vc,
                              float* __restrict__ max20) {
    __shared__ unsigned sc[256];
    __shared__ double ss[256];
    int t = threadIdx.x;
    unsigned pc = 0;
    double ps = 0.0;
    // group t covers bins 8191-32t .. 8191-32t-31 (descending)
    for (int j = 0; j < 32; ++j) {
        int b = (NBINS - 1) - (t * 32 + j);
        pc += cnt[b];
        ps += (double)sm[b];
    }
    sc[t] = pc; ss[t] = ps;
    __syncthreads();
    for (int off = 1; off < 256; off <<= 1) {
        unsigned cadd = (t >= off) ? sc[t - off] : 0u;
        double sadd = (t >= off) ? ss[t - off] : 0.0;
        __syncthreads();
        sc[t] += cadd; ss[t] += sadd;
        __syncthreads();
    }
    unsigned incl_c = sc[t];
    double incl_s = ss[t];
    unsigned excl_c = incl_c - pc;
    double excl_s = incl_s - ps;

    unsigned C = *vc;
    int k = (int)ceilf((float)C * 0.2f);   // replicate jnp: f32 multiply then ceil
    if (k <= 0) {
        if (t == 0) *max20 = 0.0f;
        return;
    }
    if (excl_c < (unsigned)k && incl_c >= (unsigned)k) {
        unsigned cum = excl_c;
        double s = excl_s;
        for (int j = 0; j < 32; ++j) {
            int b = (NBINS - 1) - (t * 32 + j);
            unsigned cb = cnt[b];
            if (cum + cb >= (unsigned)k) {
                unsigned r = (unsigned)k - cum;
                double partial = cb ? (double)sm[b] * ((double)r / (double)cb) : 0.0;
                *max20 = (float)((s + partial) / (double)k);
                break;
            }
            cum += cb;
            s += (double)sm[b];
        }
    }
}

// ---------------- Kernel C: heatmap_r = clip(h/max20,0,1); copy junctions ----
__global__ void refine_kernel(const float* __restrict__ hm,
                              const float* __restrict__ junc,
                              const float* __restrict__ max20p,
                              float* __restrict__ out_junc,
                              float* __restrict__ out_hm) {
    int idx = blockIdx.x * blockDim.x + threadIdx.x;
    float m = *max20p;
    if (idx < 2 * NJ) out_junc[idx] = junc[idx];
    if (idx < HH * WW) {
        float v = hm[idx] / m;
        out_hm[idx] = fminf(fmaxf(v, 0.0f), 1.0f);
    }
}

// ---------------- Kernel D: per-pair keep + line scores + line_map ----------
// grid (250,250); block of 64 (= 1 wave). i=blockIdx.x, j=blockIdx.y, j>i.
__device__ __constant__ float OFFH[29] = {
    -3,
    -2,-2,-2,-2,-2,
    -1,-1,-1,-1,-1,
     0, 0, 0, 0, 0, 0, 0,
     1, 1, 1, 1, 1,
     2, 2, 2, 2, 2,
     3
};
__device__ __constant__ float OFFW[29] = {
     0,
    -2,-1, 0, 1, 2,
    -2,-1, 0, 1, 2,
    -3,-2,-1, 0, 1, 2, 3,
    -2,-1, 0, 1, 2,
    -2,-1, 0, 1, 2,
     0
};

__global__ __launch_bounds__(64) void pairs_kernel(const float* __restrict__ junc,
                                                   const float* __restrict__ hm_r,
                                                   float* __restrict__ line_map) {
    int i = blockIdx.x;
    int j = blockIdx.y;
    if (j <= i) return;
    int lane = threadIdx.x;

    float sh = junc[2 * i], sw = junc[2 * i + 1];
    float eh = junc[2 * j], ew = junc[2 * j + 1];
    float dh = eh - sh, dw = ew - sw;
    float L2 = dh * dh + dw * dw;
    float L = sqrtf(L2);

    // ---- keep: count other junctions lying on the segment (dist<=3, proj in [0,1])
    int cnt = 0;
    for (int n = lane; n < NJ; n += 64) {
        if (n == i || n == j) continue;
        float vh = junc[2 * n] - sh;
        float vw = junc[2 * n + 1] - sw;
        float dot = vh * dh + vw * dw;            // = (cand.dir) * L
        if (dot >= 0.0f && dot <= L2) {
            float cn2 = vh * vh + vw * vw;
            float dist2 = cn2 - (dot * dot) / L2; // orthogonal distance^2
            if (dist2 <= 9.0f) cnt++;
        }
    }

    // ---- per-sample local max over circular patch
    float t = (float)lane / 63.0f;
    float ch = fminf(fmaxf(sh * t + eh * (1.0f - t), 0.0f), (float)(HH - 1));
    float cw = fminf(fmaxf(sw * t + ew * (1.0f - t), 0.0f), (float)(WW - 1));
    float rh = rintf(ch), rw = rintf(cw);   // round half-to-even, matches jnp.round
    float fh = ch - rh, fw = cw - rw;
    float nl = L / 724.07734f;              // sqrt(512^2+512^2) rounded to f32
    float th = 0.70710678f + 2.0f * nl;
    float th2 = th * th;

    float lmax = 0.0f;
#pragma unroll
    for (int p = 0; p < 29; ++p) {
        float oh = OFFH[p], ow = OFFW[p];
        float ddh = fh - oh, ddw = fw - ow;
        float d2 = ddh * ddh + ddw * ddw;
        int ph = (int)fminf(fmaxf(rh + oh, 0.0f), (float)(HH - 1));
        int pw = (int)fminf(fmaxf(rw + ow, 0.0f), (float)(WW - 1));
        float v = hm_r[(ph << 9) + pw];
        v = (d2 < th2) ? v : 0.0f;
        lmax = fmaxf(lmax, v);
    }

    // ---- wave reduction: sum(lmax), count(lmax>0.5), sum(cnt)
    float ssum = lmax;
    int inl = (lmax > 0.5f) ? 1 : 0;
    for (int off = 32; off; off >>= 1) {
        ssum += __shfl_down(ssum, off);
        inl  += __shfl_down(inl, off);
        cnt  += __shfl_down(cnt, off);
    }

    if (lane == 0) {
        float mean_score = ssum / 64.0f;
        bool detected = (mean_score > 0.5f) && (inl == 64) && (cnt <= 0);
        if (detected) {
            line_map[i * NJ + j] = 1.0f;
            line_map[j * NJ + i] = 1.0f;
        }
    }
}

extern "C" void kernel_launch(void* const* d_in, const int* in_sizes, int n_in,
                              void* d_out, int out_size, void* d_ws, size_t ws_size,
                              hipStream_t stream) {
    const float* junc = (const float*)d_in[0];   // [250,2]
    const float* hm   = (const float*)d_in[1];   // [512,512]
    float* out = (float*)d_out;
    float* out_lm   = out;                 // 62500 (line_map as 0.0/1.0 floats)
    float* out_junc = out + NJ * NJ;       // 500
    float* out_hm   = out + NJ * NJ + 2 * NJ; // 262144

    unsigned* hist_cnt = (unsigned*)d_ws;                          // 8192 u32
    float*    hist_sum = (float*)((char*)d_ws + NBINS * 4);        // 8192 f32
    unsigned* valid_cnt = (unsigned*)((char*)d_ws + NBINS * 8);    // 1 u32
    float*    max20     = (float*)((char*)d_ws + NBINS * 8 + 4);   // 1 f32

    hipMemsetAsync(d_ws, 0, NBINS * 8 + 8, stream);
    hipMemsetAsync(d_out, 0, NJ * NJ * sizeof(float), stream);

    hist_kernel<<<256, 256, 0, stream>>>(hm, hist_cnt, hist_sum, valid_cnt);
    select_kernel<<<1, 256, 0, stream>>>(hist_cnt, hist_sum, valid_cnt, max20);
    refine_kernel<<<1024, 256, 0, stream>>>(hm, junc, max20, out_junc, out_hm);
    pairs_kernel<<<dim3(NJ, NJ), 64, 0, stream>>>(junc, out_hm, out_lm);
}

// Round 2
// 124.034 us; speedup vs baseline: 1.5222x; 1.5222x over previous
//
#include <hip/hip_runtime.h>
#include <hip/hip_bf16.h>

#define HH 512
#define WW 512
#define NJ 250
#define NBINS 8192
#define NPAIR 31125   // 250*249/2

// ---------------- Kernel A: histogram of valid heatmap values ----------------
__global__ void hist_kernel(const float* __restrict__ hm,
                            unsigned* __restrict__ cnt,
                            float* __restrict__ sm,
                            unsigned* __restrict__ vc) {
    int idx = blockIdx.x * blockDim.x + threadIdx.x;
    int stride = gridDim.x * blockDim.x;
    unsigned local_valid = 0;
    for (int i = idx; i < HH * WW; i += stride) {
        float v = hm[i];
        if (v > 0.001f) {
            local_valid++;
            int b = (int)(v * (float)NBINS);
            b = min(max(b, 0), NBINS - 1);
            atomicAdd(&cnt[b], 1u);
            atomicAdd(&sm[b], v);
        }
    }
    atomicAdd(vc, local_valid);
}

// ---------------- Kernel B: find top-k sum -> max20 ----------------
__global__ void select_kernel(const unsigned* __restrict__ cnt,
                              const float* __restrict__ sm,
                              const unsigned* __restrict__ vc,
                              float* __restrict__ max20) {
    __shared__ unsigned sc[256];
    __shared__ double ss[256];
    int t = threadIdx.x;
    unsigned pc = 0;
    double ps = 0.0;
    for (int j = 0; j < 32; ++j) {
        int b = (NBINS - 1) - (t * 32 + j);
        pc += cnt[b];
        ps += (double)sm[b];
    }
    sc[t] = pc; ss[t] = ps;
    __syncthreads();
    for (int off = 1; off < 256; off <<= 1) {
        unsigned cadd = (t >= off) ? sc[t - off] : 0u;
        double sadd = (t >= off) ? ss[t - off] : 0.0;
        __syncthreads();
        sc[t] += cadd; ss[t] += sadd;
        __syncthreads();
    }
    unsigned incl_c = sc[t];
    double incl_s = ss[t];
    unsigned excl_c = incl_c - pc;
    double excl_s = incl_s - ps;

    unsigned C = *vc;
    int k = (int)ceilf((float)C * 0.2f);
    if (k <= 0) {
        if (t == 0) *max20 = 0.0f;
        return;
    }
    if (excl_c < (unsigned)k && incl_c >= (unsigned)k) {
        unsigned cum = excl_c;
        double s = excl_s;
        for (int j = 0; j < 32; ++j) {
            int b = (NBINS - 1) - (t * 32 + j);
            unsigned cb = cnt[b];
            if (cum + cb >= (unsigned)k) {
                unsigned r = (unsigned)k - cum;
                double partial = cb ? (double)sm[b] * ((double)r / (double)cb) : 0.0;
                *max20 = (float)((s + partial) / (double)k);
                break;
            }
            cum += cb;
            s += (double)sm[b];
        }
    }
}

// ------- Kernel C: heatmap_r = clip(h/max20,0,1); copy junctions; zero lm ----
__global__ void refine_kernel(const float* __restrict__ hm,
                              const float* __restrict__ junc,
                              const float* __restrict__ max20p,
                              float* __restrict__ out_junc,
                              float* __restrict__ out_hm,
                              float* __restrict__ out_lm) {
    int idx = blockIdx.x * blockDim.x + threadIdx.x;
    float m = *max20p;
    if (idx < 2 * NJ) out_junc[idx] = junc[idx];
    if (idx < NJ * NJ) out_lm[idx] = 0.0f;
    if (idx < HH * WW) {
        float v = hm[idx] / m;
        out_hm[idx] = fminf(fmaxf(v, 0.0f), 1.0f);
    }
}

// ---------------- Kernel D: per-pair keep + early-exit detect ----------------
// Patch offsets sorted by ascending radius^2 (0,1,2,4,5,8,9) — 29 entries.
__device__ __constant__ float POH[29] = {
    0,  0, 0, 1,-1,  1, 1,-1,-1,  0, 0, 2,-2,
    1, 1,-1,-1, 2, 2,-2,-2,  2, 2,-2,-2,  0, 0, 3,-3
};
__device__ __constant__ float POW[29] = {
    0,  1,-1, 0, 0,  1,-1, 1,-1,  2,-2, 0, 0,
    2,-2, 2,-2, 1,-1, 1,-1,  2,-2, 2,-2,  3,-3, 0, 0
};

__global__ __launch_bounds__(64) void pairs_kernel(const float* __restrict__ junc,
                                                   const float* __restrict__ hm_r,
                                                   float* __restrict__ line_map) {
    int m = blockIdx.x;
    int lane = threadIdx.x;

    // decode triangular index: row i, col j (j>i); base(i) = i*(499-i)/2
    int i = (int)((499.0 - sqrt(499.0 * 499.0 - 8.0 * (double)m)) * 0.5);
    if (i < 0) i = 0;
    while ((i + 1) * (499 - (i + 1)) / 2 <= m) ++i;
    while (i * (499 - i) / 2 > m) --i;
    int j = i + 1 + (m - i * (499 - i) / 2);

    float sh = junc[2 * i], sw = junc[2 * i + 1];
    float eh = junc[2 * j], ew = junc[2 * j + 1];
    float dh = eh - sh, dw = ew - sw;
    float L2 = dh * dh + dw * dw;
    float L = sqrtf(L2);

    // ---- keep: any other junction on the segment (dist<=3, proj in [0,1])?
    int cnt = 0;
    for (int n = lane; n < NJ; n += 64) {
        if (n == i || n == j) continue;
        float vh = junc[2 * n] - sh;
        float vw = junc[2 * n + 1] - sw;
        float dot = vh * dh + vw * dw;
        if (dot >= 0.0f && dot <= L2) {
            float cn2 = vh * vh + vw * vw;
            float dist2 = cn2 - (dot * dot) / L2;
            if (dist2 <= 9.0f) cnt++;
        }
    }
    if (__any(cnt > 0)) return;   // keep==false -> not detected

    // ---- per-sample early-exit: lane resolves when a masked value > 0.5
    float t = (float)lane / 63.0f;
    float ch = fminf(fmaxf(sh * t + eh * (1.0f - t), 0.0f), (float)(HH - 1));
    float cw = fminf(fmaxf(sw * t + ew * (1.0f - t), 0.0f), (float)(WW - 1));
    float rh = rintf(ch), rw = rintf(cw);
    float fh = ch - rh, fw = cw - rw;
    float nl = L / 724.07734f;
    float th = 0.70710678f + 2.0f * nl;
    float th2 = th * th;

    bool need = true;  // lane has not yet found a masked value > 0.5
    for (int p = 0; p < 29; ++p) {
        if (!__any(need)) break;
        if (need) {
            float oh = POH[p], ow = POW[p];
            float ddh = fh - oh, ddw = fw - ow;
            if (ddh * ddh + ddw * ddw < th2) {
                int ph = (int)fminf(fmaxf(rh + oh, 0.0f), (float)(HH - 1));
                int pw = (int)fminf(fmaxf(rw + ow, 0.0f), (float)(WW - 1));
                if (hm_r[(ph << 9) + pw] > 0.5f) need = false;
            }
        }
    }
    // a lane still needing means its exact lmax <= 0.5 -> inlier test fails
    if (__any(need)) return;

    if (lane == 0) {
        line_map[i * NJ + j] = 1.0f;
        line_map[j * NJ + i] = 1.0f;
    }
}

extern "C" void kernel_launch(void* const* d_in, const int* in_sizes, int n_in,
                              void* d_out, int out_size, void* d_ws, size_t ws_size,
                              hipStream_t stream) {
    const float* junc = (const float*)d_in[0];   // [250,2]
    const float* hm   = (const float*)d_in[1];   // [512,512]
    float* out = (float*)d_out;
    float* out_lm   = out;                     // 62500 floats (0.0/1.0)
    float* out_junc = out + NJ * NJ;           // 500
    float* out_hm   = out + NJ * NJ + 2 * NJ;  // 262144

    unsigned* hist_cnt  = (unsigned*)d_ws;                         // 8192 u32
    float*    hist_sum  = (float*)((char*)d_ws + NBINS * 4);       // 8192 f32
    unsigned* valid_cnt = (unsigned*)((char*)d_ws + NBINS * 8);    // 1 u32
    float*    max20     = (float*)((char*)d_ws + NBINS * 8 + 4);   // 1 f32

    hipMemsetAsync(d_ws, 0, NBINS * 8 + 8, stream);

    hist_kernel<<<256, 256, 0, stream>>>(hm, hist_cnt, hist_sum, valid_cnt);
    select_kernel<<<1, 256, 0, stream>>>(hist_cnt, hist_sum, valid_cnt, max20);
    refine_kernel<<<1024, 256, 0, stream>>>(hm, junc, max20, out_junc, out_hm, out_lm);
    pairs_kernel<<<NPAIR, 64, 0, stream>>>(junc, out_hm, out_lm);
}